// Round 7
// baseline (2260.728 us; speedup 1.0000x reference)
//
#include <hip/hip_runtime.h>
#include <cstdint>
#include <cstddef>

#define N_NODES_C 100000
#define N_EDGES_C 1600000
#define N_VOCAB_C 50000
#define DIM_C 128
#define NEG_SLOPE_C 0.2f
#define NB_C 391   // ceil(N_NODES / 256) buckets of 256 nodes

typedef unsigned short u16;
typedef unsigned int u32;
typedef u16 u16x8 __attribute__((ext_vector_type(8)));
typedef __bf16 bf16x8v __attribute__((ext_vector_type(8)));
typedef float f32x4 __attribute__((ext_vector_type(4)));

__device__ __forceinline__ unsigned f2u(float x) { union { float f; unsigned u; } c; c.f = x; return c.u; }
__device__ __forceinline__ float u2f(unsigned u) { union { float f; unsigned u; } c; c.u = u; return c.f; }
__device__ __forceinline__ u16 bf_rn(float x) {
    unsigned u = f2u(x);
    return (u16)((u + 0x7FFFu + ((u >> 16) & 1u)) >> 16);
}
// split x = hi + lo, hi = truncate-to-bf16 (hi exact), lo = RN-bf16 of residual
__device__ __forceinline__ void bf_split(float x, u16& h, u16& l) {
    unsigned u = f2u(x);
    h = (u16)(u >> 16);
    float lo = x - u2f(u & 0xFFFF0000u);
    l = bf_rn(lo);
}

__device__ __forceinline__ f32x4 mfma_bf16(u16x8 a, u16x8 b, f32x4 c) {
    return __builtin_amdgcn_mfma_f32_16x16x32_bf16(
        __builtin_bit_cast(bf16x8v, a), __builtin_bit_cast(bf16x8v, b), c, 0, 0, 0);
}

// ---------------------------------------------------------------------------
// W fragment precompute (once; shared by both layers) + zero bucket counters.
// ---------------------------------------------------------------------------
__global__ __launch_bounds__(256) void wfrag_kernel(const float* __restrict__ W,
                                                    u16* __restrict__ Whf,
                                                    u16* __restrict__ Wlf,
                                                    int* __restrict__ bcz) {
    int f = blockIdx.x * 256 + threadIdx.x;
    if (f < 2 * NB_C) bcz[f] = 0;
    if (f >= 2048) return;
    int ks = f >> 9, ct = (f >> 6) & 7, ln = f & 63;
    int col = ct * 16 + (ln & 15);
    int k0 = ks * 32 + (ln >> 4) * 8;
    u16x8 hv, lv;
#pragma unroll
    for (int e = 0; e < 8; e++) {
        u16 h, l;
        bf_split(W[(size_t)(k0 + e) * 128 + col], h, l);
        hv[e] = h; lv[e] = l;
    }
    *(u16x8*)(Whf + (size_t)f * 8) = hv;
    *(u16x8*)(Wlf + (size_t)f * 8) = lv;
}

// ---------------------------------------------------------------------------
// MFMA GEMM (bf16x3 ~ f32): XW = X @ W, 64 rows x 128 cols / block.
// ---------------------------------------------------------------------------
__global__ __launch_bounds__(256) void gemm_mfma(const float* __restrict__ X,
                                                 const u16* __restrict__ Whf,
                                                 const u16* __restrict__ Wlf,
                                                 const float* __restrict__ a_src,
                                                 const float* __restrict__ a_dst,
                                                 float* __restrict__ XW,
                                                 float* __restrict__ s_src,
                                                 float* __restrict__ s_dst, int n) {
    __shared__ uint4 lds_q[6144];                 // 96 KB
    u16* Ah = (u16*)lds_q;                        // 16 KB
    u16* Al = (u16*)((char*)lds_q + 16384);       // 16 KB
    u16* Bh = (u16*)((char*)lds_q + 32768);       // 32 KB
    u16* Bl = (u16*)((char*)lds_q + 65536);       // 32 KB
    float* wb = (float*)lds_q;                    // reused: [64][132]

    const int t = threadIdx.x;
    const int row0 = blockIdx.x * 64;

    {
        const uint4* gh = (const uint4*)Whf;
        const uint4* gl = (const uint4*)Wlf;
        uint4* lh = (uint4*)Bh;
        uint4* ll = (uint4*)Bl;
#pragma unroll
        for (int i = 0; i < 8; i++) {
            lh[t + 256 * i] = gh[t + 256 * i];
            ll[t + 256 * i] = gl[t + 256 * i];
        }
    }
    {
        for (int i = 0; i < 4; i++) {
            int f = t + 256 * i;
            int g = f >> 8, ks = (f >> 6) & 3, ln = f & 63;
            int r = row0 + g * 16 + (ln & 15);
            int k0 = ks * 32 + (ln >> 4) * 8;
            float4 v0 = make_float4(0.f, 0.f, 0.f, 0.f), v1 = v0;
            if (r < n) {
                v0 = *(const float4*)(X + (size_t)r * 128 + k0);
                v1 = *(const float4*)(X + (size_t)r * 128 + k0 + 4);
            }
            float xe[8] = {v0.x, v0.y, v0.z, v0.w, v1.x, v1.y, v1.z, v1.w};
            u16x8 hv, lv;
#pragma unroll
            for (int e = 0; e < 8; e++) {
                u16 h, l;
                bf_split(xe[e], h, l);
                hv[e] = h; lv[e] = l;
            }
            *(u16x8*)(Ah + (size_t)f * 8) = hv;
            *(u16x8*)(Al + (size_t)f * 8) = lv;
        }
    }
    __syncthreads();

    const int g = t >> 6, l = t & 63;
    f32x4 acc[8];
#pragma unroll
    for (int ct = 0; ct < 8; ct++)
#pragma unroll
        for (int j = 0; j < 4; j++) acc[ct][j] = 0.f;

    for (int ks = 0; ks < 4; ks++) {
        u16x8 ah = *(u16x8*)(Ah + ((size_t)((g * 4 + ks) * 64 + l)) * 8);
        u16x8 al = *(u16x8*)(Al + ((size_t)((g * 4 + ks) * 64 + l)) * 8);
#pragma unroll
        for (int ct = 0; ct < 8; ct++) {
            u16x8 bh = *(u16x8*)(Bh + ((size_t)((ks * 8 + ct) * 64 + l)) * 8);
            u16x8 bl = *(u16x8*)(Bl + ((size_t)((ks * 8 + ct) * 64 + l)) * 8);
            acc[ct] = mfma_bf16(ah, bh, acc[ct]);
            acc[ct] = mfma_bf16(al, bh, acc[ct]);
            acc[ct] = mfma_bf16(ah, bl, acc[ct]);
        }
    }

    const int l15 = l & 15, lg = l >> 4;
    {
        float ss[4] = {0.f, 0.f, 0.f, 0.f};
        float sd[4] = {0.f, 0.f, 0.f, 0.f};
#pragma unroll
        for (int ct = 0; ct < 8; ct++) {
            float as = a_src[ct * 16 + l15];
            float ad = a_dst[ct * 16 + l15];
#pragma unroll
            for (int j = 0; j < 4; j++) {
                ss[j] += acc[ct][j] * as;
                sd[j] += acc[ct][j] * ad;
            }
        }
#pragma unroll
        for (int off = 1; off < 16; off <<= 1)
#pragma unroll
            for (int j = 0; j < 4; j++) {
                ss[j] += __shfl_xor(ss[j], off);
                sd[j] += __shfl_xor(sd[j], off);
            }
        if (l15 == 0) {
#pragma unroll
            for (int j = 0; j < 4; j++) {
                int r = row0 + g * 16 + lg * 4 + j;
                if (r < n) { s_src[r] = ss[j]; s_dst[r] = sd[j]; }
            }
        }
    }

    __syncthreads();   // all waves done with A/B frags before overwrite
#pragma unroll
    for (int ct = 0; ct < 8; ct++)
#pragma unroll
        for (int j = 0; j < 4; j++)
            wb[(size_t)(g * 16 + lg * 4 + j) * 132 + ct * 16 + l15] = acc[ct][j];
#pragma unroll
    for (int i = 0; i < 8; i++) {
        int idx = i * 64 + l;
        int rr = idx >> 5, c4 = idx & 31;
        int r = row0 + g * 16 + rr;
        if (r < n)
            *(float4*)(XW + (size_t)r * 128 + c4 * 4) =
                *(float4*)(wb + (size_t)(g * 16 + rr) * 132 + c4 * 4);
    }
}

// ---------------------------------------------------------------------------
// Bucketed CSR build (counting sort by dst>>8).
// Kills the 16x write amplification of direct atomic fill: bucket appends are
// tail-sequential (16 u32/line), and final col_src placement is L2-local.
// ---------------------------------------------------------------------------
__global__ void bucket_count(const int* __restrict__ dst1, const int* __restrict__ dst2,
                             int* __restrict__ bc1, int* __restrict__ bc2,
                             int E, int cb) {
    int b = blockIdx.x;
    const int* dst; int* c;
    if (b < cb) { dst = dst1; c = bc1; }
    else        { dst = dst2; c = bc2; b -= cb; }
    int i0 = (b * 256 + threadIdx.x) * 4;
    if (i0 + 3 < E) {
        int4 d = *(const int4*)(dst + i0);
        atomicAdd(&c[d.x >> 8], 1);
        atomicAdd(&c[d.y >> 8], 1);
        atomicAdd(&c[d.z >> 8], 1);
        atomicAdd(&c[d.w >> 8], 1);
    } else {
        for (int k = 0; k < 4 && i0 + k < E; k++) atomicAdd(&c[dst[i0 + k] >> 8], 1);
    }
}

// 2 blocks: exclusive scan of NB_C bucket counts -> bbase[NB+1], tail copy
__global__ __launch_bounds__(256) void bucket_scan(
        const int* __restrict__ bc1, int* __restrict__ bbase1, int* __restrict__ tail1,
        const int* __restrict__ bc2, int* __restrict__ bbase2, int* __restrict__ tail2,
        int nb, int E) {
    const int* bc; int* bbase; int* tail;
    if (blockIdx.x == 0) { bc = bc1; bbase = bbase1; tail = tail1; }
    else                 { bc = bc2; bbase = bbase2; tail = tail2; }
    __shared__ int ls[256];
    int t = threadIdx.x;
    int a0 = (2 * t < nb) ? bc[2 * t] : 0;
    int a1 = (2 * t + 1 < nb) ? bc[2 * t + 1] : 0;
    int pair = a0 + a1;
    ls[t] = pair;
    __syncthreads();
    for (int off = 1; off < 256; off <<= 1) {
        int x = (t >= off) ? ls[t - off] : 0;
        __syncthreads();
        ls[t] += x;
        __syncthreads();
    }
    int excl = ls[t] - pair;
    if (2 * t < nb)     { bbase[2 * t] = excl;          tail[2 * t] = excl; }
    if (2 * t + 1 < nb) { bbase[2 * t + 1] = excl + a0; tail[2 * t + 1] = excl + a0; }
    if (t == 255) bbase[nb] = E;
}

// append packed (dstLow<<24 | src) at the bucket tail (tail holds global pos)
__global__ void bucket_scatter(const int* __restrict__ s1, const int* __restrict__ d1,
                               int* __restrict__ tail1, u32* __restrict__ bk1,
                               const int* __restrict__ s2, const int* __restrict__ d2,
                               int* __restrict__ tail2, u32* __restrict__ bk2,
                               int E, int cb) {
    int b = blockIdx.x;
    const int* src; const int* dst; int* tail; u32* bk;
    if (b < cb) { src = s1; dst = d1; tail = tail1; bk = bk1; }
    else        { src = s2; dst = d2; tail = tail2; bk = bk2; b -= cb; }
    int i0 = (b * 256 + threadIdx.x) * 4;
    if (i0 + 3 < E) {
        int4 s = *(const int4*)(src + i0);
        int4 d = *(const int4*)(dst + i0);
        int p;
        p = atomicAdd(&tail[d.x >> 8], 1); bk[p] = ((u32)(d.x & 255) << 24) | (u32)s.x;
        p = atomicAdd(&tail[d.y >> 8], 1); bk[p] = ((u32)(d.y & 255) << 24) | (u32)s.y;
        p = atomicAdd(&tail[d.z >> 8], 1); bk[p] = ((u32)(d.z & 255) << 24) | (u32)s.z;
        p = atomicAdd(&tail[d.w >> 8], 1); bk[p] = ((u32)(d.w & 255) << 24) | (u32)s.w;
    } else {
        for (int k = 0; k < 4 && i0 + k < E; k++) {
            int dd = dst[i0 + k];
            int p = atomicAdd(&tail[dd >> 8], 1);
            bk[p] = ((u32)(dd & 255) << 24) | (u32)src[i0 + k];
        }
    }
}

// one block per (set, bucket): LDS histogram + scan -> row_start and col_src
__global__ __launch_bounds__(256) void csr_finalize(
        const u32* __restrict__ bk1, const int* __restrict__ bbase1,
        const u32* __restrict__ bk2, const int* __restrict__ bbase2,
        int* __restrict__ rowst1, int* __restrict__ col1,
        int* __restrict__ rowst2, int* __restrict__ col2,
        int n, int E, int nb) {
    int blk = blockIdx.x;
    int s = blk >= nb;
    int b = s ? blk - nb : blk;
    const u32* bk = s ? bk2 : bk1;
    const int* bbase = s ? bbase2 : bbase1;
    int* rowst = s ? rowst2 : rowst1;
    int* col = s ? col2 : col1;
    int t = threadIdx.x;

    __shared__ int hist[256];
    __shared__ int run[256];
    hist[t] = 0;
    __syncthreads();
    int e0 = bbase[b], e1 = bbase[b + 1];
    for (int i = e0 + t; i < e1; i += 256) atomicAdd(&hist[bk[i] >> 24], 1);
    __syncthreads();
    int own = hist[t];
    for (int off = 1; off < 256; off <<= 1) {
        int x = (t >= off) ? hist[t - off] : 0;
        __syncthreads();
        hist[t] += x;
        __syncthreads();
    }
    int excl = hist[t] - own;
    int node = (b << 8) + t;
    if (node < n) rowst[node] = e0 + excl;
    run[t] = e0 + excl;
    __syncthreads();
    for (int i = e0 + t; i < e1; i += 256) {
        u32 v = bk[i];
        int p = atomicAdd(&run[v >> 24], 1);
        col[p] = (int)(v & 0xFFFFFFu);
    }
    if (b == nb - 1 && t == 0) rowst[n] = E;
}

// ---------------------------------------------------------------------------
// GAT aggregation: one wave per destination node (16 edges in flight)
// ---------------------------------------------------------------------------
__global__ __launch_bounds__(256) void gat_agg(const float* __restrict__ XW,
                                               const int* __restrict__ row_start,
                                               const int* __restrict__ col_src,
                                               const float* __restrict__ s_src,
                                               const float* __restrict__ s_dst,
                                               const float* __restrict__ bias,
                                               float* __restrict__ OUT, int n) {
    int v = (blockIdx.x * 256 + threadIdx.x) >> 6;
    int lane = threadIdx.x & 63;
    if (v >= n) return;
    const int h = lane >> 5;
    const int sl = lane & 31;

    float sdv = s_dst[v];

    float e0 = s_src[v] + sdv;
    e0 = (e0 > 0.f) ? e0 : NEG_SLOPE_C * e0;
    float p0 = __expf(e0);
    float4 xself = *(const float4*)(XW + (size_t)v * 128 + sl * 4);
    float w0 = (h == 0) ? p0 : 0.f;
    float4 acc;
    acc.x = w0 * xself.x; acc.y = w0 * xself.y;
    acc.z = w0 * xself.z; acc.w = w0 * xself.w;
    float psum_l = (lane == 0) ? p0 : 0.f;

    const int beg = row_start[v];
    const int end = row_start[v + 1];

    for (int base = beg; base < end; base += 64) {
        int m = end - base;
        if (m > 64) m = 64;
        int u_l = (lane < m) ? col_src[base + lane] : v;
        float s = s_src[u_l] + sdv;
        s = (s > 0.f) ? s : NEG_SLOPE_C * s;
        float pe = (lane < m) ? __expf(s) : 0.f;
        psum_l += pe;

        int i = 0;
        for (; i + 16 <= m; i += 16) {
            int uu[8]; float qq[8]; float4 xx[8];
#pragma unroll
            for (int k = 0; k < 8; k++) {
                int e = i + 2 * k + h;
                uu[k] = __shfl(u_l, e);
                qq[k] = __shfl(pe, e);
            }
#pragma unroll
            for (int k = 0; k < 8; k++)
                xx[k] = *(const float4*)(XW + (size_t)uu[k] * 128 + sl * 4);
#pragma unroll
            for (int k = 0; k < 8; k++) {
                acc.x = fmaf(qq[k], xx[k].x, acc.x);
                acc.y = fmaf(qq[k], xx[k].y, acc.y);
                acc.z = fmaf(qq[k], xx[k].z, acc.z);
                acc.w = fmaf(qq[k], xx[k].w, acc.w);
            }
        }
        for (; i < m; i += 2) {
            int e = i + h;
            int ec = (e < m) ? e : 0;
            int u = __shfl(u_l, ec);
            float q = __shfl(pe, ec);
            if (e >= m) q = 0.f;
            float4 xu = *(const float4*)(XW + (size_t)u * 128 + sl * 4);
            acc.x = fmaf(q, xu.x, acc.x);
            acc.y = fmaf(q, xu.y, acc.y);
            acc.z = fmaf(q, xu.z, acc.z);
            acc.w = fmaf(q, xu.w, acc.w);
        }
    }

    acc.x += __shfl_xor(acc.x, 32);
    acc.y += __shfl_xor(acc.y, 32);
    acc.z += __shfl_xor(acc.z, 32);
    acc.w += __shfl_xor(acc.w, 32);
    float ps = psum_l;
#pragma unroll
    for (int off = 32; off; off >>= 1) ps += __shfl_xor(ps, off);

    if (h == 0) {
        float inv = 1.0f / ps;
        float4 b4 = *(const float4*)(bias + sl * 4);
        float4 o;
        o.x = acc.x * inv + b4.x;
        o.y = acc.y * inv + b4.y;
        o.z = acc.z * inv + b4.z;
        o.w = acc.w * inv + b4.w;
        *(float4*)(OUT + (size_t)v * 128 + sl * 4) = o;
    }
}

// ---------------------------------------------------------------------------
// Final gather
// ---------------------------------------------------------------------------
__global__ __launch_bounds__(256) void gather_rows(const float* __restrict__ H,
                                                   const int* __restrict__ idx,
                                                   float* __restrict__ out, int n) {
    int t = blockIdx.x * 256 + threadIdx.x;
    int r = t >> 5;
    int l = t & 31;
    if (r >= n) return;
    int v = idx[r];
    float4 x = *(const float4*)(H + (size_t)v * 128 + l * 4);
    *(float4*)(out + (size_t)r * 128 + l * 4) = x;
}

// ---------------------------------------------------------------------------
// Launcher
// ---------------------------------------------------------------------------
extern "C" void kernel_launch(void* const* d_in, const int* in_sizes, int n_in,
                              void* d_out, int out_size, void* d_ws, size_t ws_size,
                              hipStream_t stream) {
    const float* emb   = (const float*)d_in[0];
    const float* W     = (const float*)d_in[1];
    const float* a_src = (const float*)d_in[2];
    const float* a_dst = (const float*)d_in[3];
    const float* bias  = (const float*)d_in[4];
    const int*   e1    = (const int*)d_in[5];
    const int*   e2    = (const int*)d_in[6];
    const int*   idx   = (const int*)d_in[7];
    float* out = (float*)d_out;

    const int n = N_NODES_C;
    const int E = N_EDGES_C;

    char* ws = (char*)d_ws;
    auto alloc = [&](size_t bytes) {
        char* p = ws;
        ws += (bytes + 511) & ~(size_t)511;
        return p;
    };
    float* A      = (float*)alloc((size_t)n * DIM_C * 4);
    float* B      = (float*)alloc((size_t)n * DIM_C * 4);
    float* s_src  = (float*)alloc((size_t)n * 4);
    float* s_dst  = (float*)alloc((size_t)n * 4);
    int*   rowst1 = (int*)  alloc((size_t)(n + 1) * 4);
    int*   rowst2 = (int*)  alloc((size_t)(n + 1) * 4);
    int*   col1   = (int*)  alloc((size_t)E * 4);
    int*   col2   = (int*)  alloc((size_t)E * 4);
    u16*   Whf    = (u16*)  alloc(32768);
    u16*   Wlf    = (u16*)  alloc(32768);
    int*   bcz    = (int*)  alloc((size_t)2 * NB_C * 4);    // bc1|bc2
    int*   bbase1 = (int*)  alloc((size_t)(NB_C + 1) * 4);
    int*   bbase2 = (int*)  alloc((size_t)(NB_C + 1) * 4);
    int*   tail1  = (int*)  alloc((size_t)NB_C * 4);
    int*   tail2  = (int*)  alloc((size_t)NB_C * 4);
    (void)ws_size; (void)in_sizes; (void)n_in; (void)out_size;

    int* bc1 = bcz;
    int* bc2 = bcz + NB_C;
    // bucketed edge arrays alias A: consumed by csr_finalize before gemm1 writes A
    u32* bk1 = (u32*)A;
    u32* bk2 = (u32*)A + E;

    const int gemm_blocks  = (n + 63) / 64;
    const int cb           = (E + 1023) / 1024;     // 4 edges/thread
    const int wave_blocks  = (n * 64 + 255) / 256;  // one wave per node
    const int gath_blocks  = (N_VOCAB_C * 32 + 255) / 256;

    const int* src1 = e1;  const int* dst1 = e1 + E;
    const int* src2 = e2;  const int* dst2 = e2 + E;

    // W fragments + zero bucket counters
    wfrag_kernel<<<8, 256, 0, stream>>>(W, Whf, Wlf, bcz);
    // bucketed CSR build for both edge sets
    bucket_count<<<2 * cb, 256, 0, stream>>>(dst1, dst2, bc1, bc2, E, cb);
    bucket_scan<<<2, 256, 0, stream>>>(bc1, bbase1, tail1, bc2, bbase2, tail2, NB_C, E);
    bucket_scatter<<<2 * cb, 256, 0, stream>>>(src1, dst1, tail1, bk1,
                                               src2, dst2, tail2, bk2, E, cb);
    csr_finalize<<<2 * NB_C, 256, 0, stream>>>(bk1, bbase1, bk2, bbase2,
                                               rowst1, col1, rowst2, col2, n, E, NB_C);
    // layer 1
    gemm_mfma<<<gemm_blocks, 256, 0, stream>>>(emb, Whf, Wlf, a_src, a_dst,
                                               A, s_src, s_dst, n);
    gat_agg<<<wave_blocks, 256, 0, stream>>>(A, rowst1, col1, s_src, s_dst,
                                             bias, B, n);
    // layer 2 (same params)
    gemm_mfma<<<gemm_blocks, 256, 0, stream>>>(B, Whf, Wlf, a_src, a_dst,
                                               A, s_src, s_dst, n);
    gat_agg<<<wave_blocks, 256, 0, stream>>>(A, rowst2, col2, s_src, s_dst,
                                             bias, B, n);
    // final vocab gather
    gather_rows<<<gath_blocks, 256, 0, stream>>>(B, idx, out, N_VOCAB_C);
}

// Round 9
// 523.864 us; speedup vs baseline: 4.3155x; 4.3155x over previous
//
#include <hip/hip_runtime.h>
#include <cstdint>
#include <cstddef>

#define N_NODES_C 100000
#define N_EDGES_C 1600000
#define N_VOCAB_C 50000
#define DIM_C 128
#define NEG_SLOPE_C 0.2f
#define NB_C 391       // ceil(N_NODES / 256) buckets of 256 nodes
#define NB_PAD 392
#define CHUNK 8192     // edges per block in the counting sort
#define NCHUNK 196     // ceil(N_EDGES / CHUNK)

typedef unsigned short u16;
typedef unsigned int u32;
typedef u16 u16x8 __attribute__((ext_vector_type(8)));
typedef __bf16 bf16x8v __attribute__((ext_vector_type(8)));
typedef float f32x4 __attribute__((ext_vector_type(4)));

__device__ __forceinline__ unsigned f2u(float x) { union { float f; unsigned u; } c; c.f = x; return c.u; }
__device__ __forceinline__ float u2f(unsigned u) { union { float f; unsigned u; } c; c.u = u; return c.f; }
__device__ __forceinline__ u16 bf_rn(float x) {
    unsigned u = f2u(x);
    return (u16)((u + 0x7FFFu + ((u >> 16) & 1u)) >> 16);
}
// split x = hi + lo, hi = truncate-to-bf16 (hi exact), lo = RN-bf16 of residual
__device__ __forceinline__ void bf_split(float x, u16& h, u16& l) {
    unsigned u = f2u(x);
    h = (u16)(u >> 16);
    float lo = x - u2f(u & 0xFFFF0000u);
    l = bf_rn(lo);
}

__device__ __forceinline__ f32x4 mfma_bf16(u16x8 a, u16x8 b, f32x4 c) {
    return __builtin_amdgcn_mfma_f32_16x16x32_bf16(
        __builtin_bit_cast(bf16x8v, a), __builtin_bit_cast(bf16x8v, b), c, 0, 0, 0);
}

// ---------------------------------------------------------------------------
// W fragment precompute (once; shared by both layers).
// ---------------------------------------------------------------------------
__global__ __launch_bounds__(256) void wfrag_kernel(const float* __restrict__ W,
                                                    u16* __restrict__ Whf,
                                                    u16* __restrict__ Wlf) {
    int f = blockIdx.x * 256 + threadIdx.x;
    if (f >= 2048) return;
    int ks = f >> 9, ct = (f >> 6) & 7, ln = f & 63;
    int col = ct * 16 + (ln & 15);
    int k0 = ks * 32 + (ln >> 4) * 8;
    u16x8 hv, lv;
#pragma unroll
    for (int e = 0; e < 8; e++) {
        u16 h, l;
        bf_split(W[(size_t)(k0 + e) * 128 + col], h, l);
        hv[e] = h; lv[e] = l;
    }
    *(u16x8*)(Whf + (size_t)f * 8) = hv;
    *(u16x8*)(Wlf + (size_t)f * 8) = lv;
}

// ---------------------------------------------------------------------------
// MFMA GEMM (bf16x3 ~ f32): XW = X @ W, 64 rows x 128 cols / block.
// ---------------------------------------------------------------------------
__global__ __launch_bounds__(256) void gemm_mfma(const float* __restrict__ X,
                                                 const u16* __restrict__ Whf,
                                                 const u16* __restrict__ Wlf,
                                                 const float* __restrict__ a_src,
                                                 const float* __restrict__ a_dst,
                                                 float* __restrict__ XW,
                                                 float* __restrict__ s_src,
                                                 float* __restrict__ s_dst, int n) {
    __shared__ uint4 lds_q[6144];                 // 96 KB
    u16* Ah = (u16*)lds_q;                        // 16 KB
    u16* Al = (u16*)((char*)lds_q + 16384);       // 16 KB
    u16* Bh = (u16*)((char*)lds_q + 32768);       // 32 KB
    u16* Bl = (u16*)((char*)lds_q + 65536);       // 32 KB
    float* wb = (float*)lds_q;                    // reused: [64][132]

    const int t = threadIdx.x;
    const int row0 = blockIdx.x * 64;

    {
        const uint4* gh = (const uint4*)Whf;
        const uint4* gl = (const uint4*)Wlf;
        uint4* lh = (uint4*)Bh;
        uint4* ll = (uint4*)Bl;
#pragma unroll
        for (int i = 0; i < 8; i++) {
            lh[t + 256 * i] = gh[t + 256 * i];
            ll[t + 256 * i] = gl[t + 256 * i];
        }
    }
    {
        for (int i = 0; i < 4; i++) {
            int f = t + 256 * i;
            int g = f >> 8, ks = (f >> 6) & 3, ln = f & 63;
            int r = row0 + g * 16 + (ln & 15);
            int k0 = ks * 32 + (ln >> 4) * 8;
            float4 v0 = make_float4(0.f, 0.f, 0.f, 0.f), v1 = v0;
            if (r < n) {
                v0 = *(const float4*)(X + (size_t)r * 128 + k0);
                v1 = *(const float4*)(X + (size_t)r * 128 + k0 + 4);
            }
            float xe[8] = {v0.x, v0.y, v0.z, v0.w, v1.x, v1.y, v1.z, v1.w};
            u16x8 hv, lv;
#pragma unroll
            for (int e = 0; e < 8; e++) {
                u16 h, l;
                bf_split(xe[e], h, l);
                hv[e] = h; lv[e] = l;
            }
            *(u16x8*)(Ah + (size_t)f * 8) = hv;
            *(u16x8*)(Al + (size_t)f * 8) = lv;
        }
    }
    __syncthreads();

    const int g = t >> 6, l = t & 63;
    f32x4 acc[8];
#pragma unroll
    for (int ct = 0; ct < 8; ct++)
#pragma unroll
        for (int j = 0; j < 4; j++) acc[ct][j] = 0.f;

    for (int ks = 0; ks < 4; ks++) {
        u16x8 ah = *(u16x8*)(Ah + ((size_t)((g * 4 + ks) * 64 + l)) * 8);
        u16x8 al = *(u16x8*)(Al + ((size_t)((g * 4 + ks) * 64 + l)) * 8);
#pragma unroll
        for (int ct = 0; ct < 8; ct++) {
            u16x8 bh = *(u16x8*)(Bh + ((size_t)((ks * 8 + ct) * 64 + l)) * 8);
            u16x8 bl = *(u16x8*)(Bl + ((size_t)((ks * 8 + ct) * 64 + l)) * 8);
            acc[ct] = mfma_bf16(ah, bh, acc[ct]);
            acc[ct] = mfma_bf16(al, bh, acc[ct]);
            acc[ct] = mfma_bf16(ah, bl, acc[ct]);
        }
    }

    const int l15 = l & 15, lg = l >> 4;
    {
        float ss[4] = {0.f, 0.f, 0.f, 0.f};
        float sd[4] = {0.f, 0.f, 0.f, 0.f};
#pragma unroll
        for (int ct = 0; ct < 8; ct++) {
            float as = a_src[ct * 16 + l15];
            float ad = a_dst[ct * 16 + l15];
#pragma unroll
            for (int j = 0; j < 4; j++) {
                ss[j] += acc[ct][j] * as;
                sd[j] += acc[ct][j] * ad;
            }
        }
#pragma unroll
        for (int off = 1; off < 16; off <<= 1)
#pragma unroll
            for (int j = 0; j < 4; j++) {
                ss[j] += __shfl_xor(ss[j], off);
                sd[j] += __shfl_xor(sd[j], off);
            }
        if (l15 == 0) {
#pragma unroll
            for (int j = 0; j < 4; j++) {
                int r = row0 + g * 16 + lg * 4 + j;
                if (r < n) { s_src[r] = ss[j]; s_dst[r] = sd[j]; }
            }
        }
    }

    __syncthreads();   // all waves done with A/B frags before overwrite
#pragma unroll
    for (int ct = 0; ct < 8; ct++)
#pragma unroll
        for (int j = 0; j < 4; j++)
            wb[(size_t)(g * 16 + lg * 4 + j) * 132 + ct * 16 + l15] = acc[ct][j];
#pragma unroll
    for (int i = 0; i < 8; i++) {
        int idx = i * 64 + l;
        int rr = idx >> 5, c4 = idx & 31;
        int r = row0 + g * 16 + rr;
        if (r < n)
            *(float4*)(XW + (size_t)r * 128 + c4 * 4) =
                *(float4*)(wb + (size_t)(g * 16 + rr) * 132 + c4 * 4);
    }
}

// ---------------------------------------------------------------------------
// Atomic-free CSR build: deterministic counting sort by bucket (dst>>8).
// count_lds -> col_scan -> bucket_scan -> scatter_lds -> csr_finalize.
// No global atomics anywhere (R7 lesson: 782-address atomic tails serialize
// at ~240ns/op -> 965us). All reservations precomputed by scans.
// ---------------------------------------------------------------------------

// per-(set,chunk) LDS histogram -> cnt_tbl[set][chunk][bucket]
__global__ __launch_bounds__(256) void count_lds(const int* __restrict__ d1,
                                                 const int* __restrict__ d2,
                                                 int* __restrict__ cnt_tbl, int E) {
    __shared__ int hist[NB_PAD];
    int b = blockIdx.x;
    int set = b >= NCHUNK;
    int chunk = set ? b - NCHUNK : b;
    const int* dst = set ? d2 : d1;
    int t = threadIdx.x;
    for (int i = t; i < NB_PAD; i += 256) hist[i] = 0;
    __syncthreads();
    int base = chunk * CHUNK;
    int cnt = E - base; if (cnt > CHUNK) cnt = CHUNK;
    for (int j = t; j < cnt; j += 256) atomicAdd(&hist[dst[base + j] >> 8], 1);
    __syncthreads();
    int* outp = cnt_tbl + ((size_t)set * NCHUNK + chunk) * NB_PAD;
    for (int i = t; i < NB_PAD; i += 256) outp[i] = hist[i];
}

// one wave per (set,bucket): exclusive scan of the bucket's column over chunks
// (in place) + bucket total -> bctot[set][bucket]
__global__ __launch_bounds__(64) void col_scan(int* __restrict__ cnt_tbl,
                                               int* __restrict__ bctot) {
    int b = blockIdx.x;
    int set = b >= NB_C;
    int bucket = set ? b - NB_C : b;
    int lane = threadIdx.x;
    int* colp = cnt_tbl + (size_t)set * NCHUNK * NB_PAD + bucket;
    int run = 0;
    for (int c0 = 0; c0 < NCHUNK; c0 += 64) {
        int c = c0 + lane;
        int v = (c < NCHUNK) ? colp[(size_t)c * NB_PAD] : 0;
        int s = v;
#pragma unroll
        for (int off = 1; off < 64; off <<= 1) {
            int x = __shfl_up(s, off);
            if (lane >= off) s += x;
        }
        if (c < NCHUNK) colp[(size_t)c * NB_PAD] = run + (s - v);
        run += __shfl(s, 63);
    }
    if (lane == 0) bctot[set * NB_C + bucket] = run;
}

// 2 blocks: exclusive scan of NB_C bucket totals -> bbase[NB_C+1]
__global__ __launch_bounds__(256) void bucket_scan(const int* __restrict__ bctot,
                                                   int* __restrict__ bbase1,
                                                   int* __restrict__ bbase2,
                                                   int nb, int E) {
    const int* bc = (blockIdx.x == 0) ? bctot : bctot + NB_C;
    int* bbase = (blockIdx.x == 0) ? bbase1 : bbase2;
    __shared__ int ls[256];
    int t = threadIdx.x;
    int a0 = (2 * t < nb) ? bc[2 * t] : 0;
    int a1 = (2 * t + 1 < nb) ? bc[2 * t + 1] : 0;
    int pair = a0 + a1;
    ls[t] = pair;
    __syncthreads();
    for (int off = 1; off < 256; off <<= 1) {
        int x = (t >= off) ? ls[t - off] : 0;
        __syncthreads();
        ls[t] += x;
        __syncthreads();
    }
    int excl = ls[t] - pair;
    if (2 * t < nb)     bbase[2 * t] = excl;
    if (2 * t + 1 < nb) bbase[2 * t + 1] = excl + a0;
    if (t == 255) bbase[nb] = E;
}

// counting-sort the chunk into LDS, flush coalesced to precomputed slots
__global__ __launch_bounds__(256) void scatter_lds(
        const int* __restrict__ s1, const int* __restrict__ d1,
        const int* __restrict__ s2, const int* __restrict__ d2,
        const int* __restrict__ cnt_tbl,
        const int* __restrict__ bbase1, const int* __restrict__ bbase2,
        u32* __restrict__ bk1, u32* __restrict__ bk2, int E) {
    __shared__ u32 sorted[CHUNK];       // 32 KB
    __shared__ u16 buckOf[CHUNK];       // 16 KB
    __shared__ int hist[512];
    __shared__ int choff[512];
    __shared__ int gb[NB_PAD];
    __shared__ int lcnt[NB_PAD];
    __shared__ int ls[256];

    int b = blockIdx.x;
    int set = b >= NCHUNK;
    int chunk = set ? b - NCHUNK : b;
    const int* src = set ? s2 : s1;
    const int* dst = set ? d2 : d1;
    const int* bbase = set ? bbase2 : bbase1;
    u32* bk = set ? bk2 : bk1;
    int t = threadIdx.x;

    for (int i = t; i < 512; i += 256) hist[i] = 0;
    for (int i = t; i < NB_PAD; i += 256) lcnt[i] = 0;
    __syncthreads();
    int base = chunk * CHUNK;
    int cnt = E - base; if (cnt > CHUNK) cnt = CHUNK;
    for (int j = t; j < cnt; j += 256) atomicAdd(&hist[dst[base + j] >> 8], 1);
    // global base per bucket: bucket base + this chunk's within-bucket offset
    const int* myoff = cnt_tbl + ((size_t)set * NCHUNK + chunk) * NB_PAD;
    for (int i = t; i < NB_C; i += 256) gb[i] = bbase[i] + myoff[i];
    __syncthreads();
    // local exclusive scan of hist (512 padded) -> choff
    int a0 = hist[2 * t], a1 = hist[2 * t + 1];
    int pair = a0 + a1;
    ls[t] = pair;
    __syncthreads();
    for (int off = 1; off < 256; off <<= 1) {
        int x = (t >= off) ? ls[t - off] : 0;
        __syncthreads();
        ls[t] += x;
        __syncthreads();
    }
    int excl = ls[t] - pair;
    choff[2 * t] = excl;
    choff[2 * t + 1] = excl + a0;
    __syncthreads();
    // place into LDS (counting sort)
    for (int j = t; j < cnt; j += 256) {
        int dd = dst[base + j];
        int ss = src[base + j];
        int bu = dd >> 8;
        int pos = choff[bu] + atomicAdd(&lcnt[bu], 1);
        sorted[pos] = ((u32)(dd & 255) << 24) | (u32)ss;
        buckOf[pos] = (u16)bu;
    }
    __syncthreads();
    // coalesced flush: consecutive i -> consecutive slots within bucket segments
    for (int i = t; i < cnt; i += 256) {
        int bu = buckOf[i];
        bk[gb[bu] + (i - choff[bu])] = sorted[i];
    }
}

// one block per (set, bucket): LDS histogram + scan -> row_start and col_src
__global__ __launch_bounds__(256) void csr_finalize(
        const u32* __restrict__ bk1, const int* __restrict__ bbase1,
        const u32* __restrict__ bk2, const int* __restrict__ bbase2,
        int* __restrict__ rowst1, int* __restrict__ col1,
        int* __restrict__ rowst2, int* __restrict__ col2,
        int n, int E, int nb) {
    int blk = blockIdx.x;
    int s = blk >= nb;
    int b = s ? blk - nb : blk;
    const u32* bk = s ? bk2 : bk1;
    const int* bbase = s ? bbase2 : bbase1;
    int* rowst = s ? rowst2 : rowst1;
    int* col = s ? col2 : col1;
    int t = threadIdx.x;

    __shared__ int hist[256];
    __shared__ int run[256];
    hist[t] = 0;
    __syncthreads();
    int e0 = bbase[b], e1 = bbase[b + 1];
    for (int i = e0 + t; i < e1; i += 256) atomicAdd(&hist[bk[i] >> 24], 1);
    __syncthreads();
    int own = hist[t];
    for (int off = 1; off < 256; off <<= 1) {
        int x = (t >= off) ? hist[t - off] : 0;
        __syncthreads();
        hist[t] += x;
        __syncthreads();
    }
    int excl = hist[t] - own;
    int node = (b << 8) + t;
    if (node < n) rowst[node] = e0 + excl;
    run[t] = e0 + excl;
    __syncthreads();
    for (int i = e0 + t; i < e1; i += 256) {
        u32 v = bk[i];
        int p = atomicAdd(&run[v >> 24], 1);
        col[p] = (int)(v & 0xFFFFFFu);
    }
    if (b == nb - 1 && t == 0) rowst[n] = E;
}

// ---------------------------------------------------------------------------
// GAT aggregation: one wave per destination node (16 edges in flight)
// ---------------------------------------------------------------------------
__global__ __launch_bounds__(256) void gat_agg(const float* __restrict__ XW,
                                               const int* __restrict__ row_start,
                                               const int* __restrict__ col_src,
                                               const float* __restrict__ s_src,
                                               const float* __restrict__ s_dst,
                                               const float* __restrict__ bias,
                                               float* __restrict__ OUT, int n) {
    int v = (blockIdx.x * 256 + threadIdx.x) >> 6;
    int lane = threadIdx.x & 63;
    if (v >= n) return;
    const int h = lane >> 5;
    const int sl = lane & 31;

    float sdv = s_dst[v];

    float e0 = s_src[v] + sdv;
    e0 = (e0 > 0.f) ? e0 : NEG_SLOPE_C * e0;
    float p0 = __expf(e0);
    float4 xself = *(const float4*)(XW + (size_t)v * 128 + sl * 4);
    float w0 = (h == 0) ? p0 : 0.f;
    float4 acc;
    acc.x = w0 * xself.x; acc.y = w0 * xself.y;
    acc.z = w0 * xself.z; acc.w = w0 * xself.w;
    float psum_l = (lane == 0) ? p0 : 0.f;

    const int beg = row_start[v];
    const int end = row_start[v + 1];

    for (int base = beg; base < end; base += 64) {
        int m = end - base;
        if (m > 64) m = 64;
        int u_l = (lane < m) ? col_src[base + lane] : v;
        float s = s_src[u_l] + sdv;
        s = (s > 0.f) ? s : NEG_SLOPE_C * s;
        float pe = (lane < m) ? __expf(s) : 0.f;
        psum_l += pe;

        int i = 0;
        for (; i + 16 <= m; i += 16) {
            int uu[8]; float qq[8]; float4 xx[8];
#pragma unroll
            for (int k = 0; k < 8; k++) {
                int e = i + 2 * k + h;
                uu[k] = __shfl(u_l, e);
                qq[k] = __shfl(pe, e);
            }
#pragma unroll
            for (int k = 0; k < 8; k++)
                xx[k] = *(const float4*)(XW + (size_t)uu[k] * 128 + sl * 4);
#pragma unroll
            for (int k = 0; k < 8; k++) {
                acc.x = fmaf(qq[k], xx[k].x, acc.x);
                acc.y = fmaf(qq[k], xx[k].y, acc.y);
                acc.z = fmaf(qq[k], xx[k].z, acc.z);
                acc.w = fmaf(qq[k], xx[k].w, acc.w);
            }
        }
        for (; i < m; i += 2) {
            int e = i + h;
            int ec = (e < m) ? e : 0;
            int u = __shfl(u_l, ec);
            float q = __shfl(pe, ec);
            if (e >= m) q = 0.f;
            float4 xu = *(const float4*)(XW + (size_t)u * 128 + sl * 4);
            acc.x = fmaf(q, xu.x, acc.x);
            acc.y = fmaf(q, xu.y, acc.y);
            acc.z = fmaf(q, xu.z, acc.z);
            acc.w = fmaf(q, xu.w, acc.w);
        }
    }

    acc.x += __shfl_xor(acc.x, 32);
    acc.y += __shfl_xor(acc.y, 32);
    acc.z += __shfl_xor(acc.z, 32);
    acc.w += __shfl_xor(acc.w, 32);
    float ps = psum_l;
#pragma unroll
    for (int off = 32; off; off >>= 1) ps += __shfl_xor(ps, off);

    if (h == 0) {
        float inv = 1.0f / ps;
        float4 b4 = *(const float4*)(bias + sl * 4);
        float4 o;
        o.x = acc.x * inv + b4.x;
        o.y = acc.y * inv + b4.y;
        o.z = acc.z * inv + b4.z;
        o.w = acc.w * inv + b4.w;
        *(float4*)(OUT + (size_t)v * 128 + sl * 4) = o;
    }
}

// ---------------------------------------------------------------------------
// Final gather
// ---------------------------------------------------------------------------
__global__ __launch_bounds__(256) void gather_rows(const float* __restrict__ H,
                                                   const int* __restrict__ idx,
                                                   float* __restrict__ out, int n) {
    int t = blockIdx.x * 256 + threadIdx.x;
    int r = t >> 5;
    int l = t & 31;
    if (r >= n) return;
    int v = idx[r];
    float4 x = *(const float4*)(H + (size_t)v * 128 + l * 4);
    *(float4*)(out + (size_t)r * 128 + l * 4) = x;
}

// ---------------------------------------------------------------------------
// Launcher
// ---------------------------------------------------------------------------
extern "C" void kernel_launch(void* const* d_in, const int* in_sizes, int n_in,
                              void* d_out, int out_size, void* d_ws, size_t ws_size,
                              hipStream_t stream) {
    const float* emb   = (const float*)d_in[0];
    const float* W     = (const float*)d_in[1];
    const float* a_src = (const float*)d_in[2];
    const float* a_dst = (const float*)d_in[3];
    const float* bias  = (const float*)d_in[4];
    const int*   e1    = (const int*)d_in[5];
    const int*   e2    = (const int*)d_in[6];
    const int*   idx   = (const int*)d_in[7];
    float* out = (float*)d_out;

    const int n = N_NODES_C;
    const int E = N_EDGES_C;

    char* ws = (char*)d_ws;
    auto alloc = [&](size_t bytes) {
        char* p = ws;
        ws += (bytes + 511) & ~(size_t)511;
        return p;
    };
    float* A       = (float*)alloc((size_t)n * DIM_C * 4);
    float* B       = (float*)alloc((size_t)n * DIM_C * 4);
    float* s_src   = (float*)alloc((size_t)n * 4);
    float* s_dst   = (float*)alloc((size_t)n * 4);
    int*   rowst1  = (int*)  alloc((size_t)(n + 1) * 4);
    int*   rowst2  = (int*)  alloc((size_t)(n + 1) * 4);
    int*   col1    = (int*)  alloc((size_t)E * 4);
    int*   col2    = (int*)  alloc((size_t)E * 4);
    u16*   Whf     = (u16*)  alloc(32768);
    u16*   Wlf     = (u16*)  alloc(32768);
    int*   cnt_tbl = (int*)  alloc((size_t)2 * NCHUNK * NB_PAD * 4);  // 613 KB
    int*   bctot   = (int*)  alloc((size_t)2 * NB_C * 4);
    int*   bbase1  = (int*)  alloc((size_t)(NB_C + 1) * 4);
    int*   bbase2  = (int*)  alloc((size_t)(NB_C + 1) * 4);
    (void)ws_size; (void)in_sizes; (void)n_in; (void)out_size;

    // bucketed edge arrays alias A: consumed by csr_finalize before gemm1 writes A
    u32* bk1 = (u32*)A;
    u32* bk2 = (u32*)A + E;

    const int gemm_blocks = (n + 63) / 64;
    const int wave_blocks = (n * 64 + 255) / 256;   // one wave per node
    const int gath_blocks = (N_VOCAB_C * 32 + 255) / 256;

    const int* src1 = e1;  const int* dst1 = e1 + E;
    const int* src2 = e2;  const int* dst2 = e2 + E;

    // W fragments
    wfrag_kernel<<<8, 256, 0, stream>>>(W, Whf, Wlf);
    // atomic-free CSR build for both edge sets
    count_lds<<<2 * NCHUNK, 256, 0, stream>>>(dst1, dst2, cnt_tbl, E);
    col_scan<<<2 * NB_C, 64, 0, stream>>>(cnt_tbl, bctot);
    bucket_scan<<<2, 256, 0, stream>>>(bctot, bbase1, bbase2, NB_C, E);
    scatter_lds<<<2 * NCHUNK, 256, 0, stream>>>(src1, dst1, src2, dst2, cnt_tbl,
                                                bbase1, bbase2, bk1, bk2, E);
    csr_finalize<<<2 * NB_C, 256, 0, stream>>>(bk1, bbase1, bk2, bbase2,
                                               rowst1, col1, rowst2, col2, n, E, NB_C);
    // layer 1
    gemm_mfma<<<gemm_blocks, 256, 0, stream>>>(emb, Whf, Wlf, a_src, a_dst,
                                               A, s_src, s_dst, n);
    gat_agg<<<wave_blocks, 256, 0, stream>>>(A, rowst1, col1, s_src, s_dst,
                                             bias, B, n);
    // layer 2 (same params)
    gemm_mfma<<<gemm_blocks, 256, 0, stream>>>(B, Whf, Wlf, a_src, a_dst,
                                               A, s_src, s_dst, n);
    gat_agg<<<wave_blocks, 256, 0, stream>>>(A, rowst2, col2, s_src, s_dst,
                                             bias, B, n);
    // final vocab gather
    gather_rows<<<gath_blocks, 256, 0, stream>>>(B, idx, out, N_VOCAB_C);
}